// Round 1
// baseline (380.861 us; speedup 1.0000x reference)
//
#include <hip/hip_runtime.h>
#include <hip/hip_bf16.h>
#include <stdint.h>

typedef __attribute__((ext_vector_type(8))) short short8;
typedef __attribute__((ext_vector_type(4))) float floatx4;

#define DEVINL static __device__ __forceinline__

DEVINL float bf2f(uint32_t u) {
  union { uint32_t i; float f; } x; x.i = u << 16; return x.f;
}
DEVINL uint16_t f2bf(float f) {
  union { float f; uint32_t i; } x; x.f = f;
  uint32_t i = x.i;
  i += 0x7fff + ((i >> 16) & 1);   // RNE
  return (uint16_t)(i >> 16);
}

// ---------------- fp32 -> bf16 elementwise (vectorized) ----------------
__global__ __launch_bounds__(256)
void k_cvt_bf16(const float* __restrict__ in, uint16_t* __restrict__ out, int n4) {
  int i = blockIdx.x * blockDim.x + threadIdx.x;
  int stride = gridDim.x * blockDim.x;
  for (; i < n4; i += stride) {
    float4 v = ((const float4*)in)[i];
    ushort4 o;
    o.x = f2bf(v.x); o.y = f2bf(v.y); o.z = f2bf(v.z); o.w = f2bf(v.w);
    ((ushort4*)out)[i] = o;
  }
}

// ---------------- fp32 [K][N] -> bf16 [N][K] transpose ----------------
__global__ __launch_bounds__(256)
void k_transpose_bf16(const float* __restrict__ in, uint16_t* __restrict__ out, int K, int N) {
  int idx = blockIdx.x * 256 + threadIdx.x;
  if (idx >= N * K) return;
  int n = idx / K;
  int k = idx - n * K;
  out[idx] = f2bf(in[(long)k * N + n]);
}

// ---------------- bf16 GEMM, C = A @ B^T (B stored [N][K]) ----------------
// m97 structure: 128x128 tile, BK=64, 4 waves (2x2), global_load_lds width 16,
// mfma_f32_16x16x32_bf16, 2-barrier loop.
template<int OUT_BF16>
__global__ __launch_bounds__(256)
void k_gemm_bt(const uint16_t* __restrict__ A,   // [M][Kd] bf16
               const uint16_t* __restrict__ B,   // [N][Kd] bf16
               void* __restrict__ Cout,          // bf16 [M][N] or fp32 [M][N]
               const float* __restrict__ bias,   // nullable, len N (fp32 path)
               int M, int N, int Kd)
{
  __shared__ uint16_t As[128 * 64];
  __shared__ uint16_t Bs[128 * 64];

  const int t  = threadIdx.x;
  const int l  = t & 63;
  const int w  = t >> 6;
  const int wm = w >> 1;          // wave row 0..1
  const int wn = w & 1;           // wave col 0..1
  const long m0 = (long)blockIdx.x * 128;
  const long n0 = (long)blockIdx.y * 128;

  floatx4 acc[4][4];
#pragma unroll
  for (int m = 0; m < 4; ++m)
#pragma unroll
    for (int n = 0; n < 4; ++n)
      acc[m][n] = (floatx4){0.f, 0.f, 0.f, 0.f};

  // staging: thread t loads 16B at global (row = t>>3 (+32*i), colbyte = (t&7)*16)
  const int sr = t >> 3;
  const int sc = (t & 7) * 8;
  const uint16_t* Ag = A + (m0 + sr) * Kd + sc;
  const uint16_t* Bg = B + (n0 + sr) * Kd + sc;
  // wave-uniform LDS base; HW adds lane*16
  char* AsB = (char*)As + w * 1024;
  char* BsB = (char*)Bs + w * 1024;

  // fragment read addresses (row-major [row][64] LDS)
  const int fr = l & 15;
  const int kg = l >> 4;
  const uint16_t* Ard = As + (wm * 64 + fr) * 64 + kg * 8;
  const uint16_t* Brd = Bs + (wn * 64 + fr) * 64 + kg * 8;

  for (int kt = 0; kt < Kd; kt += 64) {
#pragma unroll
    for (int i = 0; i < 4; ++i) {
      __builtin_amdgcn_global_load_lds(
          (const __attribute__((address_space(1))) void*)(Ag + kt + (long)32 * i * Kd),
          (__attribute__((address_space(3))) void*)(AsB + i * 4096), 16, 0, 0);
    }
#pragma unroll
    for (int i = 0; i < 4; ++i) {
      __builtin_amdgcn_global_load_lds(
          (const __attribute__((address_space(1))) void*)(Bg + kt + (long)32 * i * Kd),
          (__attribute__((address_space(3))) void*)(BsB + i * 4096), 16, 0, 0);
    }
    __syncthreads();

#pragma unroll
    for (int kk = 0; kk < 2; ++kk) {
      short8 af[4], bfv[4];
#pragma unroll
      for (int m = 0; m < 4; ++m)
        af[m] = *(const short8*)(Ard + m * 16 * 64 + kk * 32);
#pragma unroll
      for (int n = 0; n < 4; ++n)
        bfv[n] = *(const short8*)(Brd + n * 16 * 64 + kk * 32);
#pragma unroll
      for (int m = 0; m < 4; ++m)
#pragma unroll
        for (int n = 0; n < 4; ++n)
          acc[m][n] = __builtin_amdgcn_mfma_f32_16x16x32_bf16(af[m], bfv[n], acc[m][n], 0, 0, 0);
    }
    __syncthreads();
  }

  // epilogue: C/D layout col = lane&15, row = (lane>>4)*4 + reg
  const int orow = (l >> 4) * 4;
  const int ocol = l & 15;
  if (OUT_BF16) {
    uint16_t* C = (uint16_t*)Cout;
#pragma unroll
    for (int m = 0; m < 4; ++m) {
      long rowb = m0 + wm * 64 + m * 16 + orow;
#pragma unroll
      for (int n = 0; n < 4; ++n) {
        long col = n0 + wn * 64 + n * 16 + ocol;
#pragma unroll
        for (int r2 = 0; r2 < 4; ++r2)
          C[(rowb + r2) * N + col] = f2bf(acc[m][n][r2]);
      }
    }
  } else {
    float* C = (float*)Cout;
#pragma unroll
    for (int m = 0; m < 4; ++m) {
      long rowb = m0 + wm * 64 + m * 16 + orow;
#pragma unroll
      for (int n = 0; n < 4; ++n) {
        long col = n0 + wn * 64 + n * 16 + ocol;
        float bv = bias ? bias[col] : 0.f;
#pragma unroll
        for (int r2 = 0; r2 < 4; ++r2)
          C[(rowb + r2) * N + col] = acc[m][n][r2] + bv;
      }
    }
  }
}

// ---------------- per-token 6-head attention ----------------
// qkv: [32768][2304] bf16, row = [q(6x128) | k(6x128) | v(6x128)]
// out: bf16 in (B,H,N,D) flat layout => ((b*6+h)*4096 + n)*128 + d
__global__ __launch_bounds__(256)
void k_attn(const uint16_t* __restrict__ qkv, uint16_t* __restrict__ outp) {
  const int token = blockIdx.x * 4 + (threadIdx.x >> 6);
  const int l = threadIdx.x & 63;
  const uint32_t* row = (const uint32_t*)(qkv + (long)token * 2304);

  float qf[6][2], kf[6][2];
#pragma unroll
  for (int h = 0; h < 6; ++h) {
    uint32_t uq = row[h * 64 + l];
    qf[h][0] = bf2f(uq & 0xffffu); qf[h][1] = bf2f(uq >> 16);
    uint32_t uk = row[384 + h * 64 + l];
    kf[h][0] = bf2f(uk & 0xffffu); kf[h][1] = bf2f(uk >> 16);
  }

  float s[36];
#pragma unroll
  for (int h = 0; h < 6; ++h)
#pragma unroll
    for (int g = 0; g < 6; ++g)
      s[h * 6 + g] = qf[h][0] * kf[g][0] + qf[h][1] * kf[g][1];

  // butterfly reduce over the 64-lane wave (all lanes end with full sums)
#pragma unroll
  for (int off = 32; off > 0; off >>= 1)
#pragma unroll
    for (int i = 0; i < 36; ++i)
      s[i] += __shfl_xor(s[i], off, 64);

  const float scale = 0.088388347648318447f;  // 128^-0.5
  float p[36];
#pragma unroll
  for (int h = 0; h < 6; ++h) {
    float mx = s[h * 6];
#pragma unroll
    for (int g = 1; g < 6; ++g) mx = fmaxf(mx, s[h * 6 + g]);
    float sum = 0.f;
#pragma unroll
    for (int g = 0; g < 6; ++g) {
      float e = __expf((s[h * 6 + g] - mx) * scale);
      p[h * 6 + g] = e; sum += e;
    }
    float inv = 1.f / sum;
#pragma unroll
    for (int g = 0; g < 6; ++g) p[h * 6 + g] *= inv;
  }

  float vf[6][2];
#pragma unroll
  for (int g = 0; g < 6; ++g) {
    uint32_t uv = row[768 + g * 64 + l];
    vf[g][0] = bf2f(uv & 0xffffu); vf[g][1] = bf2f(uv >> 16);
  }

  const int b = token >> 12, nn = token & 4095;
  uint32_t* ob = (uint32_t*)outp;
#pragma unroll
  for (int h = 0; h < 6; ++h) {
    float o0 = 0.f, o1 = 0.f;
#pragma unroll
    for (int g = 0; g < 6; ++g) { o0 += p[h * 6 + g] * vf[g][0]; o1 += p[h * 6 + g] * vf[g][1]; }
    ob[((long)(b * 6 + h) * 4096 + nn) * 64 + l] =
        (uint32_t)f2bf(o0) | ((uint32_t)f2bf(o1) << 16);
  }
}

extern "C" void kernel_launch(void* const* d_in, const int* in_sizes, int n_in,
                              void* d_out, int out_size, void* d_ws, size_t ws_size,
                              hipStream_t stream) {
  const float* x      = (const float*)d_in[0];
  const float* w_qkv  = (const float*)d_in[1];
  const float* w_proj = (const float*)d_in[2];
  const float* b_proj = (const float*)d_in[3];
  float* out = (float*)d_out;

  const int Cc = 768, C3 = 2304;
  const int Mtok = in_sizes[0] / Cc;  // 32768

  // ws layout (bytes): att_bf aliases x_bf (x_bf dead after GEMM1)
  char* ws = (char*)d_ws;
  uint16_t* x_bf   = (uint16_t*)ws;                            // 50,331,648
  uint16_t* att_bf = x_bf;                                     // reuse
  uint16_t* qkv_bf = (uint16_t*)(ws + 50331648);               // 150,994,944
  uint16_t* wqkvT  = (uint16_t*)(ws + 50331648 + 150994944);   // 3,538,944
  uint16_t* wprojT = (uint16_t*)(ws + 50331648 + 150994944 + 3538944); // 1,179,648
  // total 206,045,184 bytes

  hipLaunchKernelGGL(k_cvt_bf16, dim3(2048), dim3(256), 0, stream,
                     x, x_bf, Mtok * Cc / 4);
  hipLaunchKernelGGL(k_transpose_bf16, dim3((C3 * Cc + 255) / 256), dim3(256), 0, stream,
                     w_qkv, wqkvT, Cc, C3);
  hipLaunchKernelGGL(k_transpose_bf16, dim3((Cc * Cc + 255) / 256), dim3(256), 0, stream,
                     w_proj, wprojT, Cc, Cc);

  hipLaunchKernelGGL((k_gemm_bt<1>), dim3(Mtok / 128, C3 / 128), dim3(256), 0, stream,
                     x_bf, wqkvT, (void*)qkv_bf, (const float*)nullptr, Mtok, C3, Cc);

  hipLaunchKernelGGL(k_attn, dim3(Mtok / 4), dim3(256), 0, stream, qkv_bf, att_bf);

  hipLaunchKernelGGL((k_gemm_bt<0>), dim3(Mtok / 128, Cc / 128), dim3(256), 0, stream,
                     att_bf, wprojT, (void*)out, b_proj, Mtok, Cc, Cc);
}

// Round 2
// 361.157 us; speedup vs baseline: 1.0546x; 1.0546x over previous
//
#include <hip/hip_runtime.h>
#include <hip/hip_bf16.h>
#include <stdint.h>

typedef __attribute__((ext_vector_type(8))) short short8;
typedef __attribute__((ext_vector_type(4))) float floatx4;

#define DEVINL static __device__ __forceinline__

DEVINL float bf2f(uint32_t u) {
  union { uint32_t i; float f; } x; x.i = u << 16; return x.f;
}
DEVINL uint16_t f2bf(float f) {
  union { float f; uint32_t i; } x; x.f = f;
  uint32_t i = x.i;
  i += 0x7fff + ((i >> 16) & 1);   // RNE
  return (uint16_t)(i >> 16);
}

// ---------------- fp32 -> bf16 elementwise (vectorized) ----------------
__global__ __launch_bounds__(256)
void k_cvt_bf16(const float* __restrict__ in, uint16_t* __restrict__ out, int n4) {
  int i = blockIdx.x * blockDim.x + threadIdx.x;
  int stride = gridDim.x * blockDim.x;
  for (; i < n4; i += stride) {
    float4 v = ((const float4*)in)[i];
    ushort4 o;
    o.x = f2bf(v.x); o.y = f2bf(v.y); o.z = f2bf(v.z); o.w = f2bf(v.w);
    ((ushort4*)out)[i] = o;
  }
}

// ---------------- fp32 [K][N] -> bf16 [N][K] transpose ----------------
__global__ __launch_bounds__(256)
void k_transpose_bf16(const float* __restrict__ in, uint16_t* __restrict__ out, int K, int N) {
  int idx = blockIdx.x * 256 + threadIdx.x;
  if (idx >= N * K) return;
  int n = idx / K;
  int k = idx - n * K;
  out[idx] = f2bf(in[(long)k * N + n]);
}

// ---------------- bf16 GEMM, C = A @ B^T (B stored [N][K]) ----------------
// 128x128 tile, BK=64, 4 waves (2x2), global_load_lds width 16,
// T3-minimum double-buffered 2-phase loop: stage(t+1) -> compute(t) -> barrier.
// 1D grid with XCD-bijective remap (m204), N-fastest within each XCD chunk.
template<int OUT_BF16>
__global__ __launch_bounds__(256)
void k_gemm_bt(const uint16_t* __restrict__ A,   // [M][Kd] bf16
               const uint16_t* __restrict__ B,   // [N][Kd] bf16
               void* __restrict__ Cout,          // bf16 [M][N] or fp32 [M][N]
               const float* __restrict__ bias,   // nullable, len N (fp32 path)
               int M, int N, int Kd, int tilesN)
{
  __shared__ uint16_t As[2][128 * 64];
  __shared__ uint16_t Bs[2][128 * 64];

  // ---- XCD-bijective grid remap (m204), nt fastest for A-panel L2 reuse ----
  const int nwg = gridDim.x;
  const int orig = blockIdx.x;
  const int q = nwg >> 3, r = nwg & 7;
  const int xcd = orig & 7, seq = orig >> 3;
  const int wgid = (xcd < r ? xcd * (q + 1) : r * (q + 1) + (xcd - r) * q) + seq;
  const int mt = wgid / tilesN;
  const int nt = wgid - mt * tilesN;

  const int t  = threadIdx.x;
  const int l  = t & 63;
  const int w  = t >> 6;
  const int wm = w >> 1;          // wave row 0..1
  const int wn = w & 1;           // wave col 0..1
  const long m0 = (long)mt * 128;
  const long n0 = (long)nt * 128;

  floatx4 acc[4][4];
#pragma unroll
  for (int m = 0; m < 4; ++m)
#pragma unroll
    for (int n = 0; n < 4; ++n)
      acc[m][n] = (floatx4){0.f, 0.f, 0.f, 0.f};

  // staging: thread t loads 16B at global (row = t>>3 (+32*i), col = (t&7)*8)
  const int sr = t >> 3;
  const int sc = (t & 7) * 8;
  const uint16_t* Ag = A + (m0 + sr) * Kd + sc;
  const uint16_t* Bg = B + (n0 + sr) * Kd + sc;

  // fragment read coords (row-major [row][64] LDS)
  const int fr = l & 15;
  const int kg = l >> 4;

  const int nK = Kd >> 6;

  // wave-uniform LDS staging bases (HW adds lane*16)
  auto stage = [&](int buf, int kt) {
    char* AsB = (char*)(&As[buf][0]) + w * 1024;
    char* BsB = (char*)(&Bs[buf][0]) + w * 1024;
    const long koff = (long)kt * 64;
#pragma unroll
    for (int i = 0; i < 4; ++i) {
      __builtin_amdgcn_global_load_lds(
          (const __attribute__((address_space(1))) void*)(Ag + koff + (long)32 * i * Kd),
          (__attribute__((address_space(3))) void*)(AsB + i * 4096), 16, 0, 0);
    }
#pragma unroll
    for (int i = 0; i < 4; ++i) {
      __builtin_amdgcn_global_load_lds(
          (const __attribute__((address_space(1))) void*)(Bg + koff + (long)32 * i * Kd),
          (__attribute__((address_space(3))) void*)(BsB + i * 4096), 16, 0, 0);
    }
  };

  // prologue: stage tile 0, drain, then 2-phase loop
  stage(0, 0);
  __syncthreads();

  int cur = 0;
  for (int kt = 0; kt < nK; ++kt) {
    if (kt + 1 < nK) stage(cur ^ 1, kt + 1);   // async loads fly under compute

    const uint16_t* Ard = &As[cur][(wm * 64 + fr) * 64 + kg * 8];
    const uint16_t* Brd = &Bs[cur][(wn * 64 + fr) * 64 + kg * 8];
#pragma unroll
    for (int kk = 0; kk < 2; ++kk) {
      short8 af[4], bfv[4];
#pragma unroll
      for (int m = 0; m < 4; ++m)
        af[m] = *(const short8*)(Ard + m * 16 * 64 + kk * 32);
#pragma unroll
      for (int n = 0; n < 4; ++n)
        bfv[n] = *(const short8*)(Brd + n * 16 * 64 + kk * 32);
#pragma unroll
      for (int m = 0; m < 4; ++m)
#pragma unroll
        for (int n = 0; n < 4; ++n)
          acc[m][n] = __builtin_amdgcn_mfma_f32_16x16x32_bf16(af[m], bfv[n], acc[m][n], 0, 0, 0);
    }
    __syncthreads();   // drains vmcnt(0): tile kt+1 resident; buf cur free to overwrite
    cur ^= 1;
  }

  // epilogue: C/D layout col = lane&15, row = (lane>>4)*4 + reg
  const int orow = (l >> 4) * 4;
  const int ocol = l & 15;
  if (OUT_BF16) {
    uint16_t* C = (uint16_t*)Cout;
#pragma unroll
    for (int m = 0; m < 4; ++m) {
      long rowb = m0 + wm * 64 + m * 16 + orow;
#pragma unroll
      for (int n = 0; n < 4; ++n) {
        long col = n0 + wn * 64 + n * 16 + ocol;
#pragma unroll
        for (int r2 = 0; r2 < 4; ++r2)
          C[(rowb + r2) * N + col] = f2bf(acc[m][n][r2]);
      }
    }
  } else {
    float* C = (float*)Cout;
#pragma unroll
    for (int m = 0; m < 4; ++m) {
      long rowb = m0 + wm * 64 + m * 16 + orow;
#pragma unroll
      for (int n = 0; n < 4; ++n) {
        long col = n0 + wn * 64 + n * 16 + ocol;
        float bv = bias ? bias[col] : 0.f;
#pragma unroll
        for (int r2 = 0; r2 < 4; ++r2)
          C[(rowb + r2) * N + col] = acc[m][n][r2] + bv;
      }
    }
  }
}

// ---------------- per-token 6-head attention ----------------
// qkv: [32768][2304] bf16, row = [q(6x128) | k(6x128) | v(6x128)]
// out: bf16 in (B,H,N,D) flat layout => ((b*6+h)*4096 + n)*128 + d
__global__ __launch_bounds__(256)
void k_attn(const uint16_t* __restrict__ qkv, uint16_t* __restrict__ outp) {
  const int token = blockIdx.x * 4 + (threadIdx.x >> 6);
  const int l = threadIdx.x & 63;
  const uint32_t* row = (const uint32_t*)(qkv + (long)token * 2304);

  float qf[6][2], kf[6][2];
#pragma unroll
  for (int h = 0; h < 6; ++h) {
    uint32_t uq = row[h * 64 + l];
    qf[h][0] = bf2f(uq & 0xffffu); qf[h][1] = bf2f(uq >> 16);
    uint32_t uk = row[384 + h * 64 + l];
    kf[h][0] = bf2f(uk & 0xffffu); kf[h][1] = bf2f(uk >> 16);
  }

  float s[36];
#pragma unroll
  for (int h = 0; h < 6; ++h)
#pragma unroll
    for (int g = 0; g < 6; ++g)
      s[h * 6 + g] = qf[h][0] * kf[g][0] + qf[h][1] * kf[g][1];

  // butterfly reduce over the 64-lane wave (all lanes end with full sums)
#pragma unroll
  for (int off = 32; off > 0; off >>= 1)
#pragma unroll
    for (int i = 0; i < 36; ++i)
      s[i] += __shfl_xor(s[i], off, 64);

  const float scale = 0.088388347648318447f;  // 128^-0.5
  float p[36];
#pragma unroll
  for (int h = 0; h < 6; ++h) {
    float mx = s[h * 6];
#pragma unroll
    for (int g = 1; g < 6; ++g) mx = fmaxf(mx, s[h * 6 + g]);
    float sum = 0.f;
#pragma unroll
    for (int g = 0; g < 6; ++g) {
      float e = __expf((s[h * 6 + g] - mx) * scale);
      p[h * 6 + g] = e; sum += e;
    }
    float inv = 1.f / sum;
#pragma unroll
    for (int g = 0; g < 6; ++g) p[h * 6 + g] *= inv;
  }

  float vf[6][2];
#pragma unroll
  for (int g = 0; g < 6; ++g) {
    uint32_t uv = row[768 + g * 64 + l];
    vf[g][0] = bf2f(uv & 0xffffu); vf[g][1] = bf2f(uv >> 16);
  }

  const int b = token >> 12, nn = token & 4095;
  uint32_t* ob = (uint32_t*)outp;
#pragma unroll
  for (int h = 0; h < 6; ++h) {
    float o0 = 0.f, o1 = 0.f;
#pragma unroll
    for (int g = 0; g < 6; ++g) { o0 += p[h * 6 + g] * vf[g][0]; o1 += p[h * 6 + g] * vf[g][1]; }
    ob[((long)(b * 6 + h) * 4096 + nn) * 64 + l] =
        (uint32_t)f2bf(o0) | ((uint32_t)f2bf(o1) << 16);
  }
}

extern "C" void kernel_launch(void* const* d_in, const int* in_sizes, int n_in,
                              void* d_out, int out_size, void* d_ws, size_t ws_size,
                              hipStream_t stream) {
  const float* x      = (const float*)d_in[0];
  const float* w_qkv  = (const float*)d_in[1];
  const float* w_proj = (const float*)d_in[2];
  const float* b_proj = (const float*)d_in[3];
  float* out = (float*)d_out;

  const int Cc = 768, C3 = 2304;
  const int Mtok = in_sizes[0] / Cc;  // 32768

  // ws layout (bytes): att_bf aliases x_bf (x_bf dead after GEMM1)
  char* ws = (char*)d_ws;
  uint16_t* x_bf   = (uint16_t*)ws;                            // 50,331,648
  uint16_t* att_bf = x_bf;                                     // reuse
  uint16_t* qkv_bf = (uint16_t*)(ws + 50331648);               // 150,994,944
  uint16_t* wqkvT  = (uint16_t*)(ws + 50331648 + 150994944);   // 3,538,944
  uint16_t* wprojT = (uint16_t*)(ws + 50331648 + 150994944 + 3538944); // 1,179,648
  // total 206,045,184 bytes

  hipLaunchKernelGGL(k_cvt_bf16, dim3(2048), dim3(256), 0, stream,
                     x, x_bf, Mtok * Cc / 4);
  hipLaunchKernelGGL(k_transpose_bf16, dim3((C3 * Cc + 255) / 256), dim3(256), 0, stream,
                     w_qkv, wqkvT, Cc, C3);
  hipLaunchKernelGGL(k_transpose_bf16, dim3((Cc * Cc + 255) / 256), dim3(256), 0, stream,
                     w_proj, wprojT, Cc, Cc);

  hipLaunchKernelGGL((k_gemm_bt<1>), dim3((Mtok / 128) * (C3 / 128)), dim3(256), 0, stream,
                     x_bf, wqkvT, (void*)qkv_bf, (const float*)nullptr, Mtok, C3, Cc, C3 / 128);

  hipLaunchKernelGGL(k_attn, dim3(Mtok / 4), dim3(256), 0, stream, qkv_bf, att_bf);

  hipLaunchKernelGGL((k_gemm_bt<0>), dim3((Mtok / 128) * (Cc / 128)), dim3(256), 0, stream,
                     att_bf, wprojT, (void*)out, b_proj, Mtok, Cc, Cc, Cc / 128);
}

// Round 3
// 330.362 us; speedup vs baseline: 1.1529x; 1.0932x over previous
//
#include <hip/hip_runtime.h>
#include <hip/hip_bf16.h>
#include <stdint.h>

typedef __attribute__((ext_vector_type(8))) short short8;
typedef __attribute__((ext_vector_type(4))) float floatx4;

#define DEVINL static __device__ __forceinline__

DEVINL float bf2f(uint32_t u) {
  union { uint32_t i; float f; } x; x.i = u << 16; return x.f;
}
DEVINL uint16_t f2bf(float f) {
  union { float f; uint32_t i; } x; x.f = f;
  uint32_t i = x.i;
  i += 0x7fff + ((i >> 16) & 1);   // RNE
  return (uint16_t)(i >> 16);
}

// ---------------- fp32 -> bf16 elementwise (vectorized) ----------------
__global__ __launch_bounds__(256)
void k_cvt_bf16(const float* __restrict__ in, uint16_t* __restrict__ out, int n4) {
  int i = blockIdx.x * blockDim.x + threadIdx.x;
  int stride = gridDim.x * blockDim.x;
  for (; i < n4; i += stride) {
    float4 v = ((const float4*)in)[i];
    ushort4 o;
    o.x = f2bf(v.x); o.y = f2bf(v.y); o.z = f2bf(v.z); o.w = f2bf(v.w);
    ((ushort4*)out)[i] = o;
  }
}

// ---------------- fp32 [K][N] -> bf16 [N][K] transpose ----------------
__global__ __launch_bounds__(256)
void k_transpose_bf16(const float* __restrict__ in, uint16_t* __restrict__ out, int K, int N) {
  int idx = blockIdx.x * 256 + threadIdx.x;
  if (idx >= N * K) return;
  int n = idx / K;
  int k = idx - n * K;
  out[idx] = f2bf(in[(long)k * N + n]);
}

// ============ 256x256 8-phase bf16 GEMM, C = A @ B^T (B stored [N][K]) ============
// T3+T4 counted-vmcnt schedule (4 phases per K-tile, 2 K-tiles per dbuf period),
// T2 (row&7)<<4 XOR swizzle (pre-swizzled global source + swizzled ds_read),
// T5 setprio around MFMA clusters. 8 waves (2M x 4N), per-wave 128x64 output.
// Stage ledger (per K-tile kt; buf cb=kt&1, nb=cb^1; t1=(kt+1)%nK, t2=(kt+2)%nK):
//   A: read A[m0-3],B[n0-1] of cb; stage Bhalf1(t1)->nb        ; MFMA Q(0,0)
//   B: read B[n2-3]          ; stage Ahalf1(t1)->nb            ; MFMA Q(0,1)
//   C: read A[m4-7]          ; stage Bhalf0(t2)->cb            ; MFMA Q(1,1)
//   D: (no reads)            ; stage Ahalf0(t2)->cb; vmcnt(4)  ; MFMA Q(1,0)
// Gate proof: at each D, 6 half-tile stages (12 loads) may be outstanding; the
// oldest 4 (8 loads) complete tile t1 => s_waitcnt vmcnt(4). Prologue identical.
template<int OUT_BF16>
__global__ __launch_bounds__(512, 2)
void k_gemm256(const uint16_t* __restrict__ A,   // [M][Kd] bf16
               const uint16_t* __restrict__ B,   // [N][Kd] bf16
               void* __restrict__ Cout,          // bf16 [M][N] or fp32 [M][N]
               const float* __restrict__ bias,   // nullable (fp32 path)
               int M, int N, int Kd, int tilesN)
{
  __shared__ uint16_t As[2][2][8192];  // [buf][half][128 rows x 64 cols]
  __shared__ uint16_t Bs[2][2][8192];

  // XCD-bijective remap (m204), N-fastest for A-panel L2 reuse
  const int nwg = gridDim.x;
  const int orig = blockIdx.x;
  const int q = nwg >> 3, r = nwg & 7;
  const int xcd = orig & 7, seq = orig >> 3;
  const int wgid = (xcd < r ? xcd * (q + 1) : r * (q + 1) + (xcd - r) * q) + seq;
  const int mt = wgid / tilesN;
  const int nt = wgid - mt * tilesN;

  const int t = threadIdx.x;
  const int l = t & 63;
  const int w = t >> 6;        // 0..7
  const int wm = w >> 2;       // A half (0..1)
  const int wn = w & 3;        // 0..3
  const long m0 = (long)mt * 256;
  const long n0 = (long)nt * 256;

  // staging constants: thread covers rows (t>>3) and (t>>3)+64 of a 128-row half.
  // Source col pre-swizzled so LDS[row][c] = G[row][c ^ ((row&7)<<4 bytes)].
  const int srow0 = t >> 3;
  const int scol  = ((l & 7) ^ (l >> 3)) * 8;    // element offset
  const int wbyte = w * 1024;                    // wave-uniform LDS offset

  const uint16_t* Abase = A + m0 * Kd;
  const uint16_t* Bbase = B + n0 * Kd;

  // ds_read constants
  const int fr = l & 15;
  const int kg = l >> 4;                         // 0..3
  const int xorv = (l & 7) << 4;                 // (row&7)<<4, row%8 == fr&7 == l&7
  const int cb0 = (kg * 16) ^ xorv;              // kk=0 byte col
  const int cb1 = (64 + kg * 16) ^ xorv;         // kk=1 byte col

  floatx4 acc[8][4];
#pragma unroll
  for (int m = 0; m < 8; ++m)
#pragma unroll
    for (int n = 0; n < 4; ++n)
      acc[m][n] = (floatx4){0.f, 0.f, 0.f, 0.f};

  const int nK = Kd >> 6;   // assumed even (K=768 -> 12)

  auto stage = [&](uint16_t* ldsHalf, const uint16_t* gHalf, int ktile) {
    const uint16_t* g0 = gHalf + (long)srow0 * Kd + ktile * 64 + scol;
    __builtin_amdgcn_global_load_lds(
        (const __attribute__((address_space(1))) void*)g0,
        (__attribute__((address_space(3))) void*)((char*)ldsHalf + wbyte), 16, 0, 0);
    __builtin_amdgcn_global_load_lds(
        (const __attribute__((address_space(1))) void*)(g0 + (long)64 * Kd),
        (__attribute__((address_space(3))) void*)((char*)ldsHalf + 8192 + wbyte), 16, 0, 0);
  };
  auto rdA = [&](int buf, int mm, int kk) -> short8 {
    const char* p = (const char*)&As[buf][wm][0] + mm * 2048 + fr * 128 + (kk ? cb1 : cb0);
    return *(const short8*)p;
  };
  auto rdB = [&](int buf, int nn, int kk) -> short8 {
    const char* p = (const char*)&Bs[buf][wn >> 1][0] + (wn & 1) * 8192 + nn * 2048 + fr * 128
                    + (kk ? cb1 : cb0);
    return *(const short8*)p;
  };

  // ---- prologue: FIFO [B0(0),A0(0),B1(0),A1(0),B0(1),A0(1)], wait oldest 8 ----
  stage(&Bs[0][0][0], Bbase, 0);
  stage(&As[0][0][0], Abase, 0);
  stage(&Bs[0][1][0], Bbase + (long)128 * Kd, 0);
  stage(&As[0][1][0], Abase + (long)128 * Kd, 0);
  {
    int t1 = 1 % nK;
    stage(&Bs[t1 & 1][0][0], Bbase, t1);
    stage(&As[t1 & 1][0][0], Abase, t1);
  }
  asm volatile("s_waitcnt vmcnt(4)" ::: "memory");
  __builtin_amdgcn_s_barrier();

  short8 a[4][2], bv0[2][2], bv1[2][2];

  for (int kt = 0; kt < nK; ++kt) {
    const int cbuf = kt & 1;
    const int nbuf = cbuf ^ 1;
    const int t1 = (kt + 1) % nK;   // parity nbuf (nK even)
    const int t2 = (kt + 2) % nK;   // parity cbuf

    // -------- phase A: 12 ds_reads; stage Bhalf1(t1); MFMA Q(0,0) --------
#pragma unroll
    for (int mm = 0; mm < 4; ++mm) { a[mm][0] = rdA(cbuf, mm, 0); a[mm][1] = rdA(cbuf, mm, 1); }
#pragma unroll
    for (int nn = 0; nn < 2; ++nn) { bv0[nn][0] = rdB(cbuf, nn, 0); bv0[nn][1] = rdB(cbuf, nn, 1); }
    stage(&Bs[nbuf][1][0], Bbase + (long)128 * Kd, t1);
    asm volatile("s_waitcnt lgkmcnt(8)" ::: "memory");
    __builtin_amdgcn_s_barrier();
    asm volatile("s_waitcnt lgkmcnt(0)" ::: "memory");
    __builtin_amdgcn_s_setprio(1);
#pragma unroll
    for (int mm = 0; mm < 4; ++mm)
#pragma unroll
      for (int nn = 0; nn < 2; ++nn) {
        acc[mm][nn] = __builtin_amdgcn_mfma_f32_16x16x32_bf16(a[mm][0], bv0[nn][0], acc[mm][nn], 0, 0, 0);
        acc[mm][nn] = __builtin_amdgcn_mfma_f32_16x16x32_bf16(a[mm][1], bv0[nn][1], acc[mm][nn], 0, 0, 0);
      }
    __builtin_amdgcn_s_setprio(0);
    __builtin_amdgcn_s_barrier();

    // -------- phase B: 4 ds_reads; stage Ahalf1(t1); MFMA Q(0,1) --------
#pragma unroll
    for (int nn = 0; nn < 2; ++nn) { bv1[nn][0] = rdB(cbuf, 2 + nn, 0); bv1[nn][1] = rdB(cbuf, 2 + nn, 1); }
    stage(&As[nbuf][1][0], Abase + (long)128 * Kd, t1);
    __builtin_amdgcn_s_barrier();
    asm volatile("s_waitcnt lgkmcnt(0)" ::: "memory");
    __builtin_amdgcn_s_setprio(1);
#pragma unroll
    for (int mm = 0; mm < 4; ++mm)
#pragma unroll
      for (int nn = 0; nn < 2; ++nn) {
        acc[mm][2 + nn] = __builtin_amdgcn_mfma_f32_16x16x32_bf16(a[mm][0], bv1[nn][0], acc[mm][2 + nn], 0, 0, 0);
        acc[mm][2 + nn] = __builtin_amdgcn_mfma_f32_16x16x32_bf16(a[mm][1], bv1[nn][1], acc[mm][2 + nn], 0, 0, 0);
      }
    __builtin_amdgcn_s_setprio(0);
    __builtin_amdgcn_s_barrier();

    // -------- phase C: 8 ds_reads (A m4-7); stage Bhalf0(t2); MFMA Q(1,1) --------
#pragma unroll
    for (int mm = 0; mm < 4; ++mm) { a[mm][0] = rdA(cbuf, 4 + mm, 0); a[mm][1] = rdA(cbuf, 4 + mm, 1); }
    stage(&Bs[cbuf][0][0], Bbase, t2);
    __builtin_amdgcn_s_barrier();
    asm volatile("s_waitcnt lgkmcnt(0)" ::: "memory");
    __builtin_amdgcn_s_setprio(1);
#pragma unroll
    for (int mm = 0; mm < 4; ++mm)
#pragma unroll
      for (int nn = 0; nn < 2; ++nn) {
        acc[4 + mm][2 + nn] = __builtin_amdgcn_mfma_f32_16x16x32_bf16(a[mm][0], bv1[nn][0], acc[4 + mm][2 + nn], 0, 0, 0);
        acc[4 + mm][2 + nn] = __builtin_amdgcn_mfma_f32_16x16x32_bf16(a[mm][1], bv1[nn][1], acc[4 + mm][2 + nn], 0, 0, 0);
      }
    __builtin_amdgcn_s_setprio(0);
    __builtin_amdgcn_s_barrier();

    // -------- phase D: stage Ahalf0(t2); vmcnt(4) gate; MFMA Q(1,0) --------
    stage(&As[cbuf][0][0], Abase, t2);
    asm volatile("s_waitcnt vmcnt(4)" ::: "memory");
    __builtin_amdgcn_s_barrier();
    __builtin_amdgcn_s_setprio(1);
#pragma unroll
    for (int mm = 0; mm < 4; ++mm)
#pragma unroll
      for (int nn = 0; nn < 2; ++nn) {
        acc[4 + mm][nn] = __builtin_amdgcn_mfma_f32_16x16x32_bf16(a[mm][0], bv0[nn][0], acc[4 + mm][nn], 0, 0, 0);
        acc[4 + mm][nn] = __builtin_amdgcn_mfma_f32_16x16x32_bf16(a[mm][1], bv0[nn][1], acc[4 + mm][nn], 0, 0, 0);
      }
    __builtin_amdgcn_s_setprio(0);
    __builtin_amdgcn_s_barrier();
  }

  // ---- epilogue: C/D layout col = lane&15, row = (lane>>4)*4 + reg ----
  const int orow = (l >> 4) * 4;
  const int ocol = l & 15;
  if (OUT_BF16) {
    uint16_t* C = (uint16_t*)Cout;
#pragma unroll
    for (int mm = 0; mm < 8; ++mm) {
      long rowb = m0 + wm * 128 + mm * 16 + orow;
#pragma unroll
      for (int nn = 0; nn < 4; ++nn) {
        long col = n0 + wn * 64 + nn * 16 + ocol;
#pragma unroll
        for (int r2 = 0; r2 < 4; ++r2)
          C[(rowb + r2) * N + col] = f2bf(acc[mm][nn][r2]);
      }
    }
  } else {
    float* C = (float*)Cout;
#pragma unroll
    for (int mm = 0; mm < 8; ++mm) {
      long rowb = m0 + wm * 128 + mm * 16 + orow;
#pragma unroll
      for (int nn = 0; nn < 4; ++nn) {
        long col = n0 + wn * 64 + nn * 16 + ocol;
        float bvv = bias ? bias[col] : 0.f;
#pragma unroll
        for (int r2 = 0; r2 < 4; ++r2)
          C[(rowb + r2) * N + col] = acc[mm][nn][r2] + bvv;
      }
    }
  }
}

// ---------------- per-token 6-head attention ----------------
// qkv: [32768][2304] bf16, row = [q(6x128) | k(6x128) | v(6x128)]
// out: bf16 in (B,H,N,D) flat layout => ((b*6+h)*4096 + n)*128 + d
__global__ __launch_bounds__(256)
void k_attn(const uint16_t* __restrict__ qkv, uint16_t* __restrict__ outp) {
  const int token = blockIdx.x * 4 + (threadIdx.x >> 6);
  const int l = threadIdx.x & 63;
  const uint32_t* row = (const uint32_t*)(qkv + (long)token * 2304);

  float qf[6][2], kf[6][2];
#pragma unroll
  for (int h = 0; h < 6; ++h) {
    uint32_t uq = row[h * 64 + l];
    qf[h][0] = bf2f(uq & 0xffffu); qf[h][1] = bf2f(uq >> 16);
    uint32_t uk = row[384 + h * 64 + l];
    kf[h][0] = bf2f(uk & 0xffffu); kf[h][1] = bf2f(uk >> 16);
  }

  float s[36];
#pragma unroll
  for (int h = 0; h < 6; ++h)
#pragma unroll
    for (int g = 0; g < 6; ++g)
      s[h * 6 + g] = qf[h][0] * kf[g][0] + qf[h][1] * kf[g][1];

#pragma unroll
  for (int off = 32; off > 0; off >>= 1)
#pragma unroll
    for (int i = 0; i < 36; ++i)
      s[i] += __shfl_xor(s[i], off, 64);

  const float scale = 0.088388347648318447f;  // 128^-0.5
  float p[36];
#pragma unroll
  for (int h = 0; h < 6; ++h) {
    float mx = s[h * 6];
#pragma unroll
    for (int g = 1; g < 6; ++g) mx = fmaxf(mx, s[h * 6 + g]);
    float sum = 0.f;
#pragma unroll
    for (int g = 0; g < 6; ++g) {
      float e = __expf((s[h * 6 + g] - mx) * scale);
      p[h * 6 + g] = e; sum += e;
    }
    float inv = 1.f / sum;
#pragma unroll
    for (int g = 0; g < 6; ++g) p[h * 6 + g] *= inv;
  }

  float vf[6][2];
#pragma unroll
  for (int g = 0; g < 6; ++g) {
    uint32_t uv = row[768 + g * 64 + l];
    vf[g][0] = bf2f(uv & 0xffffu); vf[g][1] = bf2f(uv >> 16);
  }

  const int b = token >> 12, nn = token & 4095;
  uint32_t* ob = (uint32_t*)outp;
#pragma unroll
  for (int h = 0; h < 6; ++h) {
    float o0 = 0.f, o1 = 0.f;
#pragma unroll
    for (int g = 0; g < 6; ++g) { o0 += p[h * 6 + g] * vf[g][0]; o1 += p[h * 6 + g] * vf[g][1]; }
    ob[((long)(b * 6 + h) * 4096 + nn) * 64 + l] =
        (uint32_t)f2bf(o0) | ((uint32_t)f2bf(o1) << 16);
  }
}

extern "C" void kernel_launch(void* const* d_in, const int* in_sizes, int n_in,
                              void* d_out, int out_size, void* d_ws, size_t ws_size,
                              hipStream_t stream) {
  const float* x      = (const float*)d_in[0];
  const float* w_qkv  = (const float*)d_in[1];
  const float* w_proj = (const float*)d_in[2];
  const float* b_proj = (const float*)d_in[3];
  float* out = (float*)d_out;

  const int Cc = 768, C3 = 2304;
  const int Mtok = in_sizes[0] / Cc;  // 32768

  char* ws = (char*)d_ws;
  uint16_t* x_bf   = (uint16_t*)ws;                            // 50,331,648 B
  uint16_t* att_bf = x_bf;                                     // reuse
  uint16_t* qkv_bf = (uint16_t*)(ws + 50331648);               // 150,994,944 B
  uint16_t* wqkvT  = (uint16_t*)(ws + 50331648 + 150994944);   // 3,538,944 B
  uint16_t* wprojT = (uint16_t*)(ws + 50331648 + 150994944 + 3538944); // 1,179,648 B

  hipLaunchKernelGGL(k_cvt_bf16, dim3(2048), dim3(256), 0, stream,
                     x, x_bf, Mtok * Cc / 4);
  hipLaunchKernelGGL(k_transpose_bf16, dim3((C3 * Cc + 255) / 256), dim3(256), 0, stream,
                     w_qkv, wqkvT, Cc, C3);
  hipLaunchKernelGGL(k_transpose_bf16, dim3((Cc * Cc + 255) / 256), dim3(256), 0, stream,
                     w_proj, wprojT, Cc, Cc);

  hipLaunchKernelGGL((k_gemm256<1>), dim3((Mtok / 256) * (C3 / 256)), dim3(512), 0, stream,
                     x_bf, wqkvT, (void*)qkv_bf, (const float*)nullptr, Mtok, C3, Cc, C3 / 256);

  hipLaunchKernelGGL(k_attn, dim3(Mtok / 4), dim3(256), 0, stream, qkv_bf, att_bf);

  hipLaunchKernelGGL((k_gemm256<0>), dim3((Mtok / 256) * (Cc / 256)), dim3(512), 0, stream,
                     att_bf, wprojT, (void*)out, b_proj, Mtok, Cc, Cc, Cc / 256);
}

// Round 4
// 282.809 us; speedup vs baseline: 1.3467x; 1.1681x over previous
//
#include <hip/hip_runtime.h>
#include <hip/hip_bf16.h>
#include <stdint.h>

typedef __attribute__((ext_vector_type(8))) short short8;
typedef __attribute__((ext_vector_type(4))) float floatx4;

#define DEVINL static __device__ __forceinline__

DEVINL float bf2f(uint32_t u) {
  union { uint32_t i; float f; } x; x.i = u << 16; return x.f;
}
DEVINL float bfu(short v) {
  union { uint32_t i; float f; } x; x.i = ((uint32_t)(uint16_t)v) << 16; return x.f;
}
DEVINL uint16_t f2bf(float f) {
  union { float f; uint32_t i; } x; x.f = f;
  uint32_t i = x.i;
  i += 0x7fff + ((i >> 16) & 1);   // RNE
  return (uint16_t)(i >> 16);
}

// ---------------- fp32 -> bf16 elementwise (vectorized) ----------------
__global__ __launch_bounds__(256)
void k_cvt_bf16(const float* __restrict__ in, uint16_t* __restrict__ out, int n4) {
  int i = blockIdx.x * blockDim.x + threadIdx.x;
  int stride = gridDim.x * blockDim.x;
  for (; i < n4; i += stride) {
    float4 v = ((const float4*)in)[i];
    ushort4 o;
    o.x = f2bf(v.x); o.y = f2bf(v.y); o.z = f2bf(v.z); o.w = f2bf(v.w);
    ((ushort4*)out)[i] = o;
  }
}

// ---------------- fp32 [K][N] -> bf16 [N][K] transpose ----------------
__global__ __launch_bounds__(256)
void k_transpose_bf16(const float* __restrict__ in, uint16_t* __restrict__ out, int K, int N) {
  int idx = blockIdx.x * 256 + threadIdx.x;
  if (idx >= N * K) return;
  int n = idx / K;
  int k = idx - n * K;
  out[idx] = f2bf(in[(long)k * N + n]);
}

// ============ 256x256 8-phase bf16 GEMM, C = A @ B^T (B stored [N][K]) ============
// T3+T4 counted-vmcnt schedule, T2 swizzle, T5 setprio (see R3 ledger comments).
// NEW (R4): LDS-staged coalesced epilogue (wave-private 4KB region in As) after
// vmcnt(0)+barrier (in-flight wrap-around global_load_lds still writes As!).
template<int OUT_BF16>
__global__ __launch_bounds__(512, 2)
void k_gemm256(const uint16_t* __restrict__ A,   // [M][Kd] bf16
               const uint16_t* __restrict__ B,   // [N][Kd] bf16
               void* __restrict__ Cout,          // bf16 [M][N] or fp32 [M][N]
               const float* __restrict__ bias,   // nullable (fp32 path)
               int M, int N, int Kd, int tilesN)
{
  __shared__ uint16_t As[2][2][8192];  // [buf][half][128 rows x 64 cols]
  __shared__ uint16_t Bs[2][2][8192];

  // XCD-bijective remap (m204), N-fastest for A-panel L2 reuse
  const int nwg = gridDim.x;
  const int orig = blockIdx.x;
  const int q = nwg >> 3, r = nwg & 7;
  const int xcd = orig & 7, seq = orig >> 3;
  const int wgid = (xcd < r ? xcd * (q + 1) : r * (q + 1) + (xcd - r) * q) + seq;
  const int mt = wgid / tilesN;
  const int nt = wgid - mt * tilesN;

  const int t = threadIdx.x;
  const int l = t & 63;
  const int w = t >> 6;        // 0..7
  const int wm = w >> 2;       // A half (0..1)
  const int wn = w & 3;        // 0..3
  const long m0 = (long)mt * 256;
  const long n0 = (long)nt * 256;

  // staging: thread covers rows (t>>3), (t>>3)+64; source col pre-swizzled so
  // LDS[row][c] = G[row][c ^ ((row&7)<<4 bytes)]
  const int srow0 = t >> 3;
  const int scol  = ((l & 7) ^ (l >> 3)) * 8;
  const int wbyte = w * 1024;

  const uint16_t* Abase = A + m0 * Kd;
  const uint16_t* Bbase = B + n0 * Kd;

  const int fr = l & 15;
  const int kg = l >> 4;
  const int xorv = (l & 7) << 4;
  const int cb0 = (kg * 16) ^ xorv;
  const int cb1 = (64 + kg * 16) ^ xorv;

  floatx4 acc[8][4];
#pragma unroll
  for (int m = 0; m < 8; ++m)
#pragma unroll
    for (int n = 0; n < 4; ++n)
      acc[m][n] = (floatx4){0.f, 0.f, 0.f, 0.f};

  const int nK = Kd >> 6;   // K=768 -> 12 (even)

  auto stage = [&](uint16_t* ldsHalf, const uint16_t* gHalf, int ktile) {
    const uint16_t* g0 = gHalf + (long)srow0 * Kd + ktile * 64 + scol;
    __builtin_amdgcn_global_load_lds(
        (const __attribute__((address_space(1))) void*)g0,
        (__attribute__((address_space(3))) void*)((char*)ldsHalf + wbyte), 16, 0, 0);
    __builtin_amdgcn_global_load_lds(
        (const __attribute__((address_space(1))) void*)(g0 + (long)64 * Kd),
        (__attribute__((address_space(3))) void*)((char*)ldsHalf + 8192 + wbyte), 16, 0, 0);
  };
  auto rdA = [&](int buf, int mm, int kk) -> short8 {
    const char* p = (const char*)&As[buf][wm][0] + mm * 2048 + fr * 128 + (kk ? cb1 : cb0);
    return *(const short8*)p;
  };
  auto rdB = [&](int buf, int nn, int kk) -> short8 {
    const char* p = (const char*)&Bs[buf][wn >> 1][0] + (wn & 1) * 8192 + nn * 2048 + fr * 128
                    + (kk ? cb1 : cb0);
    return *(const short8*)p;
  };

  // prologue: FIFO [B0(0),A0(0),B1(0),A1(0),B0(1),A0(1)], wait oldest 8
  stage(&Bs[0][0][0], Bbase, 0);
  stage(&As[0][0][0], Abase, 0);
  stage(&Bs[0][1][0], Bbase + (long)128 * Kd, 0);
  stage(&As[0][1][0], Abase + (long)128 * Kd, 0);
  {
    int t1 = 1 % nK;
    stage(&Bs[t1 & 1][0][0], Bbase, t1);
    stage(&As[t1 & 1][0][0], Abase, t1);
  }
  asm volatile("s_waitcnt vmcnt(4)" ::: "memory");
  __builtin_amdgcn_s_barrier();

  short8 a[4][2], bv0[2][2], bv1[2][2];

  for (int kt = 0; kt < nK; ++kt) {
    const int cbuf = kt & 1;
    const int nbuf = cbuf ^ 1;
    const int t1 = (kt + 1) % nK;
    const int t2 = (kt + 2) % nK;

    // phase A: 12 ds_reads; stage Bhalf1(t1); MFMA Q(0,0)
#pragma unroll
    for (int mm = 0; mm < 4; ++mm) { a[mm][0] = rdA(cbuf, mm, 0); a[mm][1] = rdA(cbuf, mm, 1); }
#pragma unroll
    for (int nn = 0; nn < 2; ++nn) { bv0[nn][0] = rdB(cbuf, nn, 0); bv0[nn][1] = rdB(cbuf, nn, 1); }
    stage(&Bs[nbuf][1][0], Bbase + (long)128 * Kd, t1);
    asm volatile("s_waitcnt lgkmcnt(8)" ::: "memory");
    __builtin_amdgcn_s_barrier();
    asm volatile("s_waitcnt lgkmcnt(0)" ::: "memory");
    __builtin_amdgcn_s_setprio(1);
#pragma unroll
    for (int mm = 0; mm < 4; ++mm)
#pragma unroll
      for (int nn = 0; nn < 2; ++nn) {
        acc[mm][nn] = __builtin_amdgcn_mfma_f32_16x16x32_bf16(a[mm][0], bv0[nn][0], acc[mm][nn], 0, 0, 0);
        acc[mm][nn] = __builtin_amdgcn_mfma_f32_16x16x32_bf16(a[mm][1], bv0[nn][1], acc[mm][nn], 0, 0, 0);
      }
    __builtin_amdgcn_s_setprio(0);
    __builtin_amdgcn_s_barrier();

    // phase B: 4 ds_reads; stage Ahalf1(t1); MFMA Q(0,1)
#pragma unroll
    for (int nn = 0; nn < 2; ++nn) { bv1[nn][0] = rdB(cbuf, 2 + nn, 0); bv1[nn][1] = rdB(cbuf, 2 + nn, 1); }
    stage(&As[nbuf][1][0], Abase + (long)128 * Kd, t1);
    __builtin_amdgcn_s_barrier();
    asm volatile("s_waitcnt lgkmcnt(0)" ::: "memory");
    __builtin_amdgcn_s_setprio(1);
#pragma unroll
    for (int mm = 0; mm < 4; ++mm)
#pragma unroll
      for (int nn = 0; nn < 2; ++nn) {
        acc[mm][2 + nn] = __builtin_amdgcn_mfma_f32_16x16x32_bf16(a[mm][0], bv1[nn][0], acc[mm][2 + nn], 0, 0, 0);
        acc[mm][2 + nn] = __builtin_amdgcn_mfma_f32_16x16x32_bf16(a[mm][1], bv1[nn][1], acc[mm][2 + nn], 0, 0, 0);
      }
    __builtin_amdgcn_s_setprio(0);
    __builtin_amdgcn_s_barrier();

    // phase C: 8 ds_reads (A m4-7); stage Bhalf0(t2); MFMA Q(1,1)
#pragma unroll
    for (int mm = 0; mm < 4; ++mm) { a[mm][0] = rdA(cbuf, 4 + mm, 0); a[mm][1] = rdA(cbuf, 4 + mm, 1); }
    stage(&Bs[cbuf][0][0], Bbase, t2);
    __builtin_amdgcn_s_barrier();
    asm volatile("s_waitcnt lgkmcnt(0)" ::: "memory");
    __builtin_amdgcn_s_setprio(1);
#pragma unroll
    for (int mm = 0; mm < 4; ++mm)
#pragma unroll
      for (int nn = 0; nn < 2; ++nn) {
        acc[4 + mm][2 + nn] = __builtin_amdgcn_mfma_f32_16x16x32_bf16(a[mm][0], bv1[nn][0], acc[4 + mm][2 + nn], 0, 0, 0);
        acc[4 + mm][2 + nn] = __builtin_amdgcn_mfma_f32_16x16x32_bf16(a[mm][1], bv1[nn][1], acc[4 + mm][2 + nn], 0, 0, 0);
      }
    __builtin_amdgcn_s_setprio(0);
    __builtin_amdgcn_s_barrier();

    // phase D: stage Ahalf0(t2); vmcnt(4) gate; MFMA Q(1,0)
    stage(&As[cbuf][0][0], Abase, t2);
    asm volatile("s_waitcnt vmcnt(4)" ::: "memory");
    __builtin_amdgcn_s_barrier();
    __builtin_amdgcn_s_setprio(1);
#pragma unroll
    for (int mm = 0; mm < 4; ++mm)
#pragma unroll
      for (int nn = 0; nn < 2; ++nn) {
        acc[4 + mm][nn] = __builtin_amdgcn_mfma_f32_16x16x32_bf16(a[mm][0], bv0[nn][0], acc[4 + mm][nn], 0, 0, 0);
        acc[4 + mm][nn] = __builtin_amdgcn_mfma_f32_16x16x32_bf16(a[mm][1], bv0[nn][1], acc[4 + mm][nn], 0, 0, 0);
      }
    __builtin_amdgcn_s_setprio(0);
    __builtin_amdgcn_s_barrier();
  }

  // ---- epilogue: drain in-flight global_load_lds (they write As!) ----
  asm volatile("s_waitcnt vmcnt(0)" ::: "memory");
  __builtin_amdgcn_s_barrier();

  // C/D frag layout: col = lane&15, row = (lane>>4)*4 + reg
  const int orow = (l >> 4) * 4;
  const int ocol = l & 15;
  if (OUT_BF16) {
    uint16_t* C = (uint16_t*)Cout;
    char* eb = (char*)&As[0][0][0] + (size_t)w * 4096;   // wave-private 4KB
    const int rr0 = l >> 3;          // 0..7
    const int cc0 = (l & 7) * 8;     // col elems
#pragma unroll
    for (int mm = 0; mm < 8; ++mm) {
#pragma unroll
      for (int nn = 0; nn < 4; ++nn)
#pragma unroll
        for (int r2 = 0; r2 < 4; ++r2) {
          int rrow = orow + r2;
          int byo = ((rrow * 64 + nn * 16 + ocol) * 2) ^ ((rrow & 7) << 4);
          *(uint16_t*)(eb + byo) = f2bf(acc[mm][nn][r2]);
        }
#pragma unroll
      for (int p = 0; p < 2; ++p) {
        int rrow = rr0 + p * 8;
        int byo = ((rrow * 64 + cc0) * 2) ^ ((rrow & 7) << 4);
        short8 vvv = *(const short8*)(eb + byo);
        *(short8*)(&C[(m0 + wm * 128 + mm * 16 + rrow) * N + n0 + wn * 64 + cc0]) = vvv;
      }
    }
  } else {
    float* C = (float*)Cout;
    float* eb = (float*)&As[0][0][0] + (size_t)w * 1024;  // wave-private 4KB
    const int rr0 = l >> 4;            // 0..3
    const int cc0 = (l & 15) * 4;
    float4 bias4 = make_float4(0.f, 0.f, 0.f, 0.f);
    if (bias) bias4 = *(const float4*)(bias + n0 + wn * 64 + cc0);
#pragma unroll
    for (int mm = 0; mm < 8; ++mm) {
#pragma unroll
      for (int nn = 0; nn < 4; ++nn)
#pragma unroll
        for (int r2 = 0; r2 < 4; ++r2)
          eb[(orow + r2) * 64 + nn * 16 + ocol] = acc[mm][nn][r2];
#pragma unroll
      for (int p = 0; p < 4; ++p) {
        int rrow = rr0 + p * 4;
        float4 vvv = *(const float4*)(eb + rrow * 64 + cc0);
        vvv.x += bias4.x; vvv.y += bias4.y; vvv.z += bias4.z; vvv.w += bias4.w;
        *(float4*)(&C[(m0 + wm * 128 + mm * 16 + rrow) * N + n0 + wn * 64 + cc0]) = vvv;
      }
    }
  }
}

// ---------------- per-token 6-head attention, 16 lanes per token ----------------
// qkv: [32768][2304] bf16 rows [q(6x128)|k(6x128)|v(6x128)]; lane i of a 16-lane
// group owns d = i*8..i*8+7 (one short8). Butterfly reduce = 4 steps within group.
// out: bf16 (B,H,N,D) flat => ((b*6+h)*4096 + n)*128 + d
__global__ __launch_bounds__(256)
void k_attn(const uint16_t* __restrict__ qkv, uint16_t* __restrict__ outp) {
  const int wid = blockIdx.x * 4 + (threadIdx.x >> 6);
  const int l = threadIdx.x & 63;
  const int sub = l >> 4;
  const int i = l & 15;
  const int token = wid * 4 + sub;
  const uint16_t* row = qkv + (long)token * 2304 + i * 8;

  short8 kv[6];
  float qf[6][8];
#pragma unroll
  for (int h = 0; h < 6; ++h) {
    short8 qv = *(const short8*)(row + h * 128);
    kv[h] = *(const short8*)(row + 768 + h * 128);
#pragma unroll
    for (int e = 0; e < 8; ++e) qf[h][e] = bfu(qv[e]);
  }

  float s[36];
#pragma unroll
  for (int g = 0; g < 6; ++g) {
    float kf[8];
#pragma unroll
    for (int e = 0; e < 8; ++e) kf[e] = bfu(kv[g][e]);
#pragma unroll
    for (int h = 0; h < 6; ++h) {
      float a = 0.f;
#pragma unroll
      for (int e = 0; e < 8; ++e) a += qf[h][e] * kf[e];
      s[h * 6 + g] = a;
    }
  }

  // butterfly within 16-lane group
#pragma unroll
  for (int off = 8; off > 0; off >>= 1)
#pragma unroll
    for (int j = 0; j < 36; ++j)
      s[j] += __shfl_xor(s[j], off, 64);

  const float scale = 0.088388347648318447f;  // 128^-0.5
  float p[36];
#pragma unroll
  for (int h = 0; h < 6; ++h) {
    float mx = s[h * 6];
#pragma unroll
    for (int g = 1; g < 6; ++g) mx = fmaxf(mx, s[h * 6 + g]);
    float sum = 0.f;
#pragma unroll
    for (int g = 0; g < 6; ++g) {
      float e = __expf((s[h * 6 + g] - mx) * scale);
      p[h * 6 + g] = e; sum += e;
    }
    float inv = 1.f / sum;
#pragma unroll
    for (int g = 0; g < 6; ++g) p[h * 6 + g] *= inv;
  }

  float o[6][8];
#pragma unroll
  for (int h = 0; h < 6; ++h)
#pragma unroll
    for (int e = 0; e < 8; ++e) o[h][e] = 0.f;
#pragma unroll
  for (int g = 0; g < 6; ++g) {
    short8 vv = *(const short8*)(row + 1536 + g * 128);
    float vf[8];
#pragma unroll
    for (int e = 0; e < 8; ++e) vf[e] = bfu(vv[e]);
#pragma unroll
    for (int h = 0; h < 6; ++h)
#pragma unroll
      for (int e = 0; e < 8; ++e) o[h][e] += p[h * 6 + g] * vf[e];
  }

  const int b = token >> 12, nn = token & 4095;
#pragma unroll
  for (int h = 0; h < 6; ++h) {
    short8 ov;
#pragma unroll
    for (int e = 0; e < 8; ++e) ov[e] = (short)f2bf(o[h][e]);
    *(short8*)(outp + ((long)(b * 6 + h) * 4096 + nn) * 128 + i * 8) = ov;
  }
}

extern "C" void kernel_launch(void* const* d_in, const int* in_sizes, int n_in,
                              void* d_out, int out_size, void* d_ws, size_t ws_size,
                              hipStream_t stream) {
  const float* x      = (const float*)d_in[0];
  const float* w_qkv  = (const float*)d_in[1];
  const float* w_proj = (const float*)d_in[2];
  const float* b_proj = (const float*)d_in[3];
  float* out = (float*)d_out;

  const int Cc = 768, C3 = 2304;
  const int Mtok = in_sizes[0] / Cc;  // 32768

  char* ws = (char*)d_ws;
  uint16_t* x_bf   = (uint16_t*)ws;                            // 50,331,648 B
  uint16_t* att_bf = x_bf;                                     // reuse
  uint16_t* qkv_bf = (uint16_t*)(ws + 50331648);               // 150,994,944 B
  uint16_t* wqkvT  = (uint16_t*)(ws + 50331648 + 150994944);   // 3,538,944 B
  uint16_t* wprojT = (uint16_t*)(ws + 50331648 + 150994944 + 3538944); // 1,179,648 B

  hipLaunchKernelGGL(k_cvt_bf16, dim3(2048), dim3(256), 0, stream,
                     x, x_bf, Mtok * Cc / 4);
  hipLaunchKernelGGL(k_transpose_bf16, dim3((C3 * Cc + 255) / 256), dim3(256), 0, stream,
                     w_qkv, wqkvT, Cc, C3);
  hipLaunchKernelGGL(k_transpose_bf16, dim3((Cc * Cc + 255) / 256), dim3(256), 0, stream,
                     w_proj, wprojT, Cc, Cc);

  hipLaunchKernelGGL((k_gemm256<1>), dim3((Mtok / 256) * (C3 / 256)), dim3(512), 0, stream,
                     x_bf, wqkvT, (void*)qkv_bf, (const float*)nullptr, Mtok, C3, Cc, C3 / 256);

  hipLaunchKernelGGL(k_attn, dim3(Mtok / 16), dim3(256), 0, stream, qkv_bf, att_bf);

  hipLaunchKernelGGL((k_gemm256<0>), dim3((Mtok / 256) * (Cc / 256)), dim3(512), 0, stream,
                     att_bf, wprojT, (void*)out, b_proj, Mtok, Cc, Cc, Cc / 256);
}

// Round 5
// 261.801 us; speedup vs baseline: 1.4548x; 1.0802x over previous
//
#include <hip/hip_runtime.h>
#include <hip/hip_bf16.h>
#include <stdint.h>

typedef __attribute__((ext_vector_type(8))) short short8;
typedef __attribute__((ext_vector_type(4))) float floatx4;

#define DEVINL static __device__ __forceinline__

DEVINL float bf2f(uint32_t u) {
  union { uint32_t i; float f; } x; x.i = u << 16; return x.f;
}
DEVINL float bfu(short v) {
  union { uint32_t i; float f; } x; x.i = ((uint32_t)(uint16_t)v) << 16; return x.f;
}
DEVINL uint16_t f2bf(float f) {
  union { float f; uint32_t i; } x; x.f = f;
  uint32_t i = x.i;
  i += 0x7fff + ((i >> 16) & 1);   // RNE
  return (uint16_t)(i >> 16);
}

// ---------------- fp32 -> bf16 elementwise (vectorized) ----------------
__global__ __launch_bounds__(256)
void k_cvt_bf16(const float* __restrict__ in, uint16_t* __restrict__ out, int n4) {
  int i = blockIdx.x * blockDim.x + threadIdx.x;
  int stride = gridDim.x * blockDim.x;
  for (; i < n4; i += stride) {
    float4 v = ((const float4*)in)[i];
    ushort4 o;
    o.x = f2bf(v.x); o.y = f2bf(v.y); o.z = f2bf(v.z); o.w = f2bf(v.w);
    ((ushort4*)out)[i] = o;
  }
}

// ---------------- fp32 [K][N] -> bf16 [N][K] transpose ----------------
__global__ __launch_bounds__(256)
void k_transpose_bf16(const float* __restrict__ in, uint16_t* __restrict__ out, int K, int N) {
  int idx = blockIdx.x * 256 + threadIdx.x;
  if (idx >= N * K) return;
  int n = idx / K;
  int k = idx - n * K;
  out[idx] = f2bf(in[(long)k * N + n]);
}

// ============ 256x256 bf16 GEMM, C = A @ B^T (B stored [N][K]) ============
// R5: merged 2-phase-per-K-tile schedule (4 barriers/K-tile instead of 8).
//   A'(kt): 16 ds_reads (A m0-3, B n0-3) ; stage B1(t1),A1(t1) ; lgkm(8) ;
//           bar ; lgkm(0) ; 32 MFMA (Q00+Q01) ; bar
//   C'(kt): 8 ds_reads (A m4-7) ; stage B0(t2) ; lgkm(0) ; bar ;
//           stage A0(t2) ; vmcnt(4) ; 32 MFMA (Q11+Q10) ; bar
// Gate proof: at C'(kt) queue = [B0(t1),A0(t1) (prev gate leftovers), B1(t1),
// A1(t1), B0(t2), A0(t2)] = 12 loads; oldest 8 = tile t1 complete => vmcnt(4).
// Hazards: A0(t2)->As[cbuf][0] only after bar#3 (all waves' lgkm(0) => all
// As[cbuf] ds_reads done). B0(t2)->Bs[cbuf][0] safe: bv reads ended in A'.
// T2 swizzle (row&7)<<4 both-sides; T5 setprio; XCD-bijective remap (m204).
template<int OUT_BF16>
__global__ __launch_bounds__(512, 2)
void k_gemm256(const uint16_t* __restrict__ A,   // [M][Kd] bf16
               const uint16_t* __restrict__ B,   // [N][Kd] bf16
               void* __restrict__ Cout,          // bf16 [M][N] or fp32 [M][N]
               const float* __restrict__ bias,   // nullable (fp32 path)
               int M, int N, int Kd, int tilesN)
{
  __shared__ uint16_t As[2][2][8192];  // [buf][half][128 rows x 64 cols]
  __shared__ uint16_t Bs[2][2][8192];

  const int nwg = gridDim.x;
  const int orig = blockIdx.x;
  const int q = nwg >> 3, r = nwg & 7;
  const int xcd = orig & 7, seq = orig >> 3;
  const int wgid = (xcd < r ? xcd * (q + 1) : r * (q + 1) + (xcd - r) * q) + seq;
  const int mt = wgid / tilesN;
  const int nt = wgid - mt * tilesN;

  const int t = threadIdx.x;
  const int l = t & 63;
  const int w = t >> 6;        // 0..7
  const int wm = w >> 2;       // A half (0..1)
  const int wn = w & 3;        // 0..3
  const long m0 = (long)mt * 256;
  const long n0 = (long)nt * 256;

  // staging: thread covers rows (t>>3), (t>>3)+64; source col pre-swizzled so
  // LDS[row][c] = G[row][c ^ ((row&7)<<4 bytes)]
  const int srow0 = t >> 3;
  const int scol  = ((l & 7) ^ (l >> 3)) * 8;
  const int wbyte = w * 1024;

  const uint16_t* Abase = A + m0 * Kd;
  const uint16_t* Bbase = B + n0 * Kd;

  const int fr = l & 15;
  const int kg = l >> 4;
  const int xorv = (l & 7) << 4;
  const int cb0 = (kg * 16) ^ xorv;
  const int cb1 = (64 + kg * 16) ^ xorv;

  floatx4 acc[8][4];
#pragma unroll
  for (int m = 0; m < 8; ++m)
#pragma unroll
    for (int n = 0; n < 4; ++n)
      acc[m][n] = (floatx4){0.f, 0.f, 0.f, 0.f};

  const int nK = Kd >> 6;   // K=768 -> 12 (even)

  auto stage = [&](uint16_t* ldsHalf, const uint16_t* gHalf, int ktile) {
    const uint16_t* g0 = gHalf + (long)srow0 * Kd + ktile * 64 + scol;
    __builtin_amdgcn_global_load_lds(
        (const __attribute__((address_space(1))) void*)g0,
        (__attribute__((address_space(3))) void*)((char*)ldsHalf + wbyte), 16, 0, 0);
    __builtin_amdgcn_global_load_lds(
        (const __attribute__((address_space(1))) void*)(g0 + (long)64 * Kd),
        (__attribute__((address_space(3))) void*)((char*)ldsHalf + 8192 + wbyte), 16, 0, 0);
  };
  auto rdA = [&](int buf, int mm, int kk) -> short8 {
    const char* p = (const char*)&As[buf][wm][0] + mm * 2048 + fr * 128 + (kk ? cb1 : cb0);
    return *(const short8*)p;
  };
  auto rdB = [&](int buf, int nn, int kk) -> short8 {
    const char* p = (const char*)&Bs[buf][wn >> 1][0] + (wn & 1) * 8192 + nn * 2048 + fr * 128
                    + (kk ? cb1 : cb0);
    return *(const short8*)p;
  };

  // prologue: FIFO [B0(0),A0(0),B1(0),A1(0),B0(1),A0(1)], wait oldest 8
  stage(&Bs[0][0][0], Bbase, 0);
  stage(&As[0][0][0], Abase, 0);
  stage(&Bs[0][1][0], Bbase + (long)128 * Kd, 0);
  stage(&As[0][1][0], Abase + (long)128 * Kd, 0);
  {
    int t1 = 1 % nK;
    stage(&Bs[t1 & 1][0][0], Bbase, t1);
    stage(&As[t1 & 1][0][0], Abase, t1);
  }
  asm volatile("s_waitcnt vmcnt(4)" ::: "memory");
  __builtin_amdgcn_s_barrier();

  short8 a[4][2], bv0[2][2], bv1[2][2];

  for (int kt = 0; kt < nK; ++kt) {
    const int cbuf = kt & 1;
    const int nbuf = cbuf ^ 1;
    const int t1 = (kt + 1) % nK;
    const int t2 = (kt + 2) % nK;

    // ---- phase A': 16 reads; stage B1(t1),A1(t1); MFMA Q00+Q01 (32) ----
#pragma unroll
    for (int mm = 0; mm < 4; ++mm) { a[mm][0] = rdA(cbuf, mm, 0); a[mm][1] = rdA(cbuf, mm, 1); }
#pragma unroll
    for (int nn = 0; nn < 2; ++nn) { bv0[nn][0] = rdB(cbuf, nn, 0); bv0[nn][1] = rdB(cbuf, nn, 1); }
#pragma unroll
    for (int nn = 0; nn < 2; ++nn) { bv1[nn][0] = rdB(cbuf, 2 + nn, 0); bv1[nn][1] = rdB(cbuf, 2 + nn, 1); }
    stage(&Bs[nbuf][1][0], Bbase + (long)128 * Kd, t1);
    stage(&As[nbuf][1][0], Abase + (long)128 * Kd, t1);
    asm volatile("s_waitcnt lgkmcnt(8)" ::: "memory");
    __builtin_amdgcn_s_barrier();
    asm volatile("s_waitcnt lgkmcnt(0)" ::: "memory");
    __builtin_amdgcn_s_setprio(1);
#pragma unroll
    for (int mm = 0; mm < 4; ++mm)
#pragma unroll
      for (int nn = 0; nn < 2; ++nn) {
        acc[mm][nn] = __builtin_amdgcn_mfma_f32_16x16x32_bf16(a[mm][0], bv0[nn][0], acc[mm][nn], 0, 0, 0);
        acc[mm][nn] = __builtin_amdgcn_mfma_f32_16x16x32_bf16(a[mm][1], bv0[nn][1], acc[mm][nn], 0, 0, 0);
        acc[mm][2 + nn] = __builtin_amdgcn_mfma_f32_16x16x32_bf16(a[mm][0], bv1[nn][0], acc[mm][2 + nn], 0, 0, 0);
        acc[mm][2 + nn] = __builtin_amdgcn_mfma_f32_16x16x32_bf16(a[mm][1], bv1[nn][1], acc[mm][2 + nn], 0, 0, 0);
      }
    __builtin_amdgcn_s_setprio(0);
    __builtin_amdgcn_s_barrier();

    // ---- phase C': 8 reads; stage B0(t2); lgkm0; bar; stage A0(t2); vmcnt(4); MFMA Q11+Q10 ----
#pragma unroll
    for (int mm = 0; mm < 4; ++mm) { a[mm][0] = rdA(cbuf, 4 + mm, 0); a[mm][1] = rdA(cbuf, 4 + mm, 1); }
    stage(&Bs[cbuf][0][0], Bbase, t2);
    asm volatile("s_waitcnt lgkmcnt(0)" ::: "memory");
    __builtin_amdgcn_s_barrier();
    stage(&As[cbuf][0][0], Abase, t2);
    asm volatile("s_waitcnt vmcnt(4)" ::: "memory");
    __builtin_amdgcn_s_setprio(1);
#pragma unroll
    for (int mm = 0; mm < 4; ++mm)
#pragma unroll
      for (int nn = 0; nn < 2; ++nn) {
        acc[4 + mm][2 + nn] = __builtin_amdgcn_mfma_f32_16x16x32_bf16(a[mm][0], bv1[nn][0], acc[4 + mm][2 + nn], 0, 0, 0);
        acc[4 + mm][2 + nn] = __builtin_amdgcn_mfma_f32_16x16x32_bf16(a[mm][1], bv1[nn][1], acc[4 + mm][2 + nn], 0, 0, 0);
        acc[4 + mm][nn] = __builtin_amdgcn_mfma_f32_16x16x32_bf16(a[mm][0], bv0[nn][0], acc[4 + mm][nn], 0, 0, 0);
        acc[4 + mm][nn] = __builtin_amdgcn_mfma_f32_16x16x32_bf16(a[mm][1], bv0[nn][1], acc[4 + mm][nn], 0, 0, 0);
      }
    __builtin_amdgcn_s_setprio(0);
    __builtin_amdgcn_s_barrier();
  }

  // ---- epilogue: drain in-flight global_load_lds (they write As/Bs!) ----
  asm volatile("s_waitcnt vmcnt(0)" ::: "memory");
  __builtin_amdgcn_s_barrier();

  // C/D frag layout: col = lane&15, row = (lane>>4)*4 + reg
  const int orow = (l >> 4) * 4;
  const int ocol = l & 15;
  if (OUT_BF16) {
    uint16_t* C = (uint16_t*)Cout;
    char* eb = (char*)&As[0][0][0] + (size_t)w * 4096;   // wave-private 4KB
    const int rr0 = l >> 3;          // 0..7
    const int cc0 = (l & 7) * 8;     // col elems
#pragma unroll
    for (int mm = 0; mm < 8; ++mm) {
#pragma unroll
      for (int nn = 0; nn < 4; ++nn)
#pragma unroll
        for (int r2 = 0; r2 < 4; ++r2) {
          int rrow = orow + r2;
          int byo = ((rrow * 64 + nn * 16 + ocol) * 2) ^ ((rrow & 7) << 4);
          *(uint16_t*)(eb + byo) = f2bf(acc[mm][nn][r2]);
        }
#pragma unroll
      for (int p = 0; p < 2; ++p) {
        int rrow = rr0 + p * 8;
        int byo = ((rrow * 64 + cc0) * 2) ^ ((rrow & 7) << 4);
        short8 vvv = *(const short8*)(eb + byo);
        *(short8*)(&C[(m0 + wm * 128 + mm * 16 + rrow) * N + n0 + wn * 64 + cc0]) = vvv;
      }
    }
  } else {
    float* C = (float*)Cout;
    float* eb = (float*)&As[0][0][0] + (size_t)w * 1024;  // wave-private 4KB
    const int rr0 = l >> 4;            // 0..3
    const int cc0 = (l & 15) * 4;
    float4 bias4 = make_float4(0.f, 0.f, 0.f, 0.f);
    if (bias) bias4 = *(const float4*)(bias + n0 + wn * 64 + cc0);
#pragma unroll
    for (int mm = 0; mm < 8; ++mm) {
#pragma unroll
      for (int nn = 0; nn < 4; ++nn)
#pragma unroll
        for (int r2 = 0; r2 < 4; ++r2)
          eb[(orow + r2) * 64 + nn * 16 + ocol] = acc[mm][nn][r2];
#pragma unroll
      for (int p = 0; p < 4; ++p) {
        int rrow = rr0 + p * 4;
        float4 vvv = *(const float4*)(eb + rrow * 64 + cc0);
        vvv.x += bias4.x; vvv.y += bias4.y; vvv.z += bias4.z; vvv.w += bias4.w;
        *(float4*)(&C[(m0 + wm * 128 + mm * 16 + rrow) * N + n0 + wn * 64 + cc0]) = vvv;
      }
    }
  }
}

// ---------------- per-token 6-head attention, 16 lanes per token ----------------
__global__ __launch_bounds__(256)
void k_attn(const uint16_t* __restrict__ qkv, uint16_t* __restrict__ outp) {
  const int wid = blockIdx.x * 4 + (threadIdx.x >> 6);
  const int l = threadIdx.x & 63;
  const int sub = l >> 4;
  const int i = l & 15;
  const int token = wid * 4 + sub;
  const uint16_t* row = qkv + (long)token * 2304 + i * 8;

  short8 kv[6];
  float qf[6][8];
#pragma unroll
  for (int h = 0; h < 6; ++h) {
    short8 qv = *(const short8*)(row + h * 128);
    kv[h] = *(const short8*)(row + 768 + h * 128);
#pragma unroll
    for (int e = 0; e < 8; ++e) qf[h][e] = bfu(qv[e]);
  }

  float s[36];
#pragma unroll
  for (int g = 0; g < 6; ++g) {
    float kf[8];
#pragma unroll
    for (int e = 0; e < 8; ++e) kf[e] = bfu(kv[g][e]);
#pragma unroll
    for (int h = 0; h < 6; ++h) {
      float a = 0.f;
#pragma unroll
      for (int e = 0; e < 8; ++e) a += qf[h][e] * kf[e];
      s[h * 6 + g] = a;
    }
  }

#pragma unroll
  for (int off = 8; off > 0; off >>= 1)
#pragma unroll
    for (int j = 0; j < 36; ++j)
      s[j] += __shfl_xor(s[j], off, 64);

  const float scale = 0.088388347648318447f;  // 128^-0.5
  float p[36];
#pragma unroll
  for (int h = 0; h < 6; ++h) {
    float mx = s[h * 6];
#pragma unroll
    for (int g = 1; g < 6; ++g) mx = fmaxf(mx, s[h * 6 + g]);
    float sum = 0.f;
#pragma unroll
    for (int g = 0; g < 6; ++g) {
      float e = __expf((s[h * 6 + g] - mx) * scale);
      p[h * 6 + g] = e; sum += e;
    }
    float inv = 1.f / sum;
#pragma unroll
    for (int g = 0; g < 6; ++g) p[h * 6 + g] *= inv;
  }

  float o[6][8];
#pragma unroll
  for (int h = 0; h < 6; ++h)
#pragma unroll
    for (int e = 0; e < 8; ++e) o[h][e] = 0.f;
#pragma unroll
  for (int g = 0; g < 6; ++g) {
    short8 vv = *(const short8*)(row + 1536 + g * 128);
    float vf[8];
#pragma unroll
    for (int e = 0; e < 8; ++e) vf[e] = bfu(vv[e]);
#pragma unroll
    for (int h = 0; h < 6; ++h)
#pragma unroll
      for (int e = 0; e < 8; ++e) o[h][e] += p[h * 6 + g] * vf[e];
  }

  const int b = token >> 12, nn = token & 4095;
#pragma unroll
  for (int h = 0; h < 6; ++h) {
    short8 ov;
#pragma unroll
    for (int e = 0; e < 8; ++e) ov[e] = (short)f2bf(o[h][e]);
    *(short8*)(outp + ((long)(b * 6 + h) * 4096 + nn) * 128 + i * 8) = ov;
  }
}

extern "C" void kernel_launch(void* const* d_in, const int* in_sizes, int n_in,
                              void* d_out, int out_size, void* d_ws, size_t ws_size,
                              hipStream_t stream) {
  const float* x      = (const float*)d_in[0];
  const float* w_qkv  = (const float*)d_in[1];
  const float* w_proj = (const float*)d_in[2];
  const float* b_proj = (const float*)d_in[3];
  float* out = (float*)d_out;

  const int Cc = 768, C3 = 2304;
  const int Mtok = in_sizes[0] / Cc;  // 32768

  char* ws = (char*)d_ws;
  uint16_t* x_bf   = (uint16_t*)ws;                            // 50,331,648 B
  uint16_t* att_bf = x_bf;                                     // reuse
  uint16_t* qkv_bf = (uint16_t*)(ws + 50331648);               // 150,994,944 B
  uint16_t* wqkvT  = (uint16_t*)(ws + 50331648 + 150994944);   // 3,538,944 B
  uint16_t* wprojT = (uint16_t*)(ws + 50331648 + 150994944 + 3538944); // 1,179,648 B

  hipLaunchKernelGGL(k_cvt_bf16, dim3(2048), dim3(256), 0, stream,
                     x, x_bf, Mtok * Cc / 4);
  hipLaunchKernelGGL(k_transpose_bf16, dim3((C3 * Cc + 255) / 256), dim3(256), 0, stream,
                     w_qkv, wqkvT, Cc, C3);
  hipLaunchKernelGGL(k_transpose_bf16, dim3((Cc * Cc + 255) / 256), dim3(256), 0, stream,
                     w_proj, wprojT, Cc, Cc);

  hipLaunchKernelGGL((k_gemm256<1>), dim3((Mtok / 256) * (C3 / 256)), dim3(512), 0, stream,
                     x_bf, wqkvT, (void*)qkv_bf, (const float*)nullptr, Mtok, C3, Cc, C3 / 256);

  hipLaunchKernelGGL(k_attn, dim3(Mtok / 16), dim3(256), 0, stream, qkv_bf, att_bf);

  hipLaunchKernelGGL((k_gemm256<0>), dim3((Mtok / 256) * (Cc / 256)), dim3(512), 0, stream,
                     att_bf, wprojT, (void*)out, b_proj, Mtok, Cc, Cc, Cc / 256);
}